// Round 7
// baseline (205.630 us; speedup 1.0000x reference)
//
#include <hip/hip_runtime.h>
#include <math.h>

#define B 8
#define D 512
#define N 1600
#define NP 1664      // padded N (13 * 128) -- physical row count of split arrays
#define NRES 40

static constexpr float EPS_K   = 1e-6f;
static constexpr float INV_T   = 10.0f;  // 1/T
static constexpr float SCALE_K = 10.0f;
static constexpr float BAND    = 0.999f; // candidate band (rel. to max K)

using f32x4 = __attribute__((ext_vector_type(4))) float;
using s8    = __attribute__((ext_vector_type(8))) short;

// ---------------- helpers ----------------
__device__ __forceinline__ unsigned short b16rn(float v) {
    unsigned int u = __float_as_uint(v);
    return (unsigned short)((u + 0x7fffu + ((u >> 16) & 1u)) >> 16);
}
__device__ __forceinline__ float b2f(unsigned short s) {
    return __uint_as_float(((unsigned int)s) << 16);
}
__device__ __forceinline__ void gload16(const void* g, void* l) {
    __builtin_amdgcn_global_load_lds(
        (const __attribute__((address_space(1))) void*)g,
        (__attribute__((address_space(3))) void*)l, 16, 0, 0);
}

// ---------------- Kernel A: split fp32 -> hi/mid bf16 transposed + norm partials ----------------
__global__ __launch_bounds__(256)
void split_transpose_kernel(const float* __restrict__ f1, const float* __restrict__ f2,
                            short* __restrict__ Xh, short* __restrict__ Xm,
                            short* __restrict__ Yh, short* __restrict__ Ym,
                            float* __restrict__ partial) {
    int bx = blockIdx.x;           // n-tile of 64 (0..25, covers NP)
    int by = blockIdx.y;           // d-tile of 64 (0..7)
    int bz = blockIdx.z;
    int b = bz & 7, which = bz >> 3;
    const float* src = which ? f2 : f1;
    short* oh = which ? Yh : Xh;
    short* om = which ? Ym : Xm;

    __shared__ float Ts[64][65];
    __shared__ float red[64][17];
    int t = threadIdx.x;
    int n0 = bx * 64, d0 = by * 64;
    bool valid = (n0 < N);         // bx==25 is the zero-pad tile
    int c4 = (t & 15) * 4, g16 = t >> 4;

    #pragma unroll
    for (int p = 0; p < 4; ++p) {
        int dl = g16 + p * 16;
        float4 v = make_float4(0.f, 0.f, 0.f, 0.f);
        if (valid) v = *(const float4*)&src[((size_t)b * D + d0 + dl) * N + n0 + c4];
        Ts[dl][c4 + 0] = v.x; Ts[dl][c4 + 1] = v.y;
        Ts[dl][c4 + 2] = v.z; Ts[dl][c4 + 3] = v.w;
    }
    __syncthreads();
    #pragma unroll
    for (int p = 0; p < 4; ++p) {
        int nl = g16 + p * 16;
        unsigned int hh[2], mm_[2];
        float ssp = 0.f;
        #pragma unroll
        for (int q = 0; q < 2; ++q) {
            unsigned int hw = 0, mw = 0;
            #pragma unroll
            for (int i = 0; i < 2; ++i) {
                float v = Ts[c4 + q * 2 + i][nl];
                ssp = fmaf(v, v, ssp);
                unsigned short h = b16rn(v);
                float r1 = v - b2f(h);
                unsigned short m_ = b16rn(r1);
                hw |= ((unsigned int)h) << (16 * i);
                mw |= ((unsigned int)m_) << (16 * i);
            }
            hh[q] = hw; mm_[q] = mw;
        }
        red[nl][c4 >> 2] = ssp;
        size_t o = ((size_t)b * NP + n0 + nl) * D + d0 + c4;
        *(uint2*)&oh[o] = make_uint2(hh[0], hh[1]);
        *(uint2*)&om[o] = make_uint2(mm_[0], mm_[1]);
    }
    __syncthreads();
    if (t < 64) {
        float s = 0.f;
        #pragma unroll
        for (int g = 0; g < 16; ++g) s += red[t][g];
        partial[(((size_t)which * 8 + b) * 8 + by) * NP + n0 + t] = s;
    }
}

// ---------------- Kernel A2: reduce norm partials ----------------
__global__ __launch_bounds__(256)
void norms_reduce_kernel(const float* __restrict__ partial,
                         float* __restrict__ norm1, float* __restrict__ norm2) {
    int id = blockIdx.x * 256 + threadIdx.x;   // over 2*B*N
    if (id >= 2 * B * N) return;
    int which = id / (B * N);
    int r = id % (B * N);
    int b = r / N, n = r % N;
    float s = 0.f;
    #pragma unroll
    for (int dt = 0; dt < 8; ++dt)
        s += partial[(((size_t)which * 8 + b) * 8 + dt) * NP + n];
    (which ? norm2 : norm1)[b * N + n] = sqrtf(s);
}

// ---------------- Kernel B (fallback path): column norms ----------------
__global__ __launch_bounds__(256)
void norms_kernel(const float* __restrict__ fs1, const float* __restrict__ fs2,
                  float* __restrict__ norm1, float* __restrict__ norm2) {
    int bid   = blockIdx.x;
    int ntile = bid % 25;
    int b     = (bid / 25) % B;
    int which = bid / (25 * B);
    const float* src = which ? fs2 : fs1;
    float*       dst = which ? norm2 : norm1;

    int t = threadIdx.x, nl = t & 63, doff = t >> 6;
    int n = ntile * 64 + nl;
    const float* base = src + (size_t)b * D * N + n;
    float acc = 0.f;
    for (int d = doff; d < D; d += 4) {
        float v = base[(size_t)d * N];
        acc = fmaf(v, v, acc);
    }
    __shared__ float red[4][64];
    red[doff][nl] = acc;
    __syncthreads();
    if (t < 64) {
        float s = red[0][t] + red[1][t] + red[2][t] + red[3][t];
        dst[b * N + ntile * 64 + t] = sqrtf(s);
    }
}

// ---------------- Kernel C: 3-product bf16x3 MFMA GEMM, 256x256, 128x64 wave tile ----------------
__device__ __forceinline__ s8 ldfrag(const short* tile, int row, int l) {
    int s = ((l >> 4) ^ (row >> 1)) & 3;   // bank-spread XOR swizzle
    return *(const s8*)(tile + row * 32 + s * 8);
}

__global__ __launch_bounds__(512, 1)
void gemm_mfma256_kernel(const short* __restrict__ Yh, const short* __restrict__ Ym,
                         const short* __restrict__ Xh, const short* __restrict__ Xm,
                         const float* __restrict__ norm1, const float* __restrict__ norm2,
                         unsigned int* __restrict__ mx, float* __restrict__ out) {
    // 2 buffers x 64KB: [Ah 16K | Am 16K | Bh 16K | Bm 16K], A/B tiles 256x32 bf16
    __shared__ short lds[2][32768];

    int lin = blockIdx.x;          // 392 = 8 XCD * 49
    int b    = lin & 7;            // one batch per XCD (T1)
    int rem  = lin >> 3;           // 0..48
    int mblk = rem % 7;            // m fastest -> X-panel L2 reuse
    int nblk = rem / 7;            // 0..6
    int m0 = mblk * 256, n0 = nblk * 256;

    int t = threadIdx.x, l = t & 63, w = t >> 6;   // 8 waves: 2M x 4N
    int mwoff = (w >> 2) * 128;    // wave tile 128x64
    int nwoff = (w & 3) * 64;
    size_t bNP = (size_t)b * NP;
    int l15 = l & 15;

    // --- staging plan: 8 gload16 per thread per K-tile (4096 loads = 64KB) ---
    // load q = j*512 + t; lane-consecutive within (j,w) => uniform LDS base + l*16B
    const short* gp[8];
    int lo[8];
    #pragma unroll
    for (int j = 0; j < 8; ++j) {
        int q = j * 512 + t;
        int tile = q >> 10;                    // 0=Ah 1=Am 2=Bh 3=Bm
        int r = q & 1023;
        int row = r >> 2, slot = r & 3;
        int slotg = slot ^ ((row >> 1) & 3);   // pre-swizzled global source
        const short* base = (tile == 0) ? Yh : (tile == 1) ? Ym : (tile == 2) ? Xh : Xm;
        int rows0 = (tile < 2) ? m0 : n0;
        int grow = rows0 + row;
        if (grow > NP - 1) grow = NP - 1;      // clamp pad rows in-bounds
        gp[j] = base + (bNP + grow) * (size_t)D + slotg * 8;
        lo[j] = tile * 8192 + row * 32 + slot * 8;   // linear LDS dest (shorts)
    }

    #define ST(buf)  { _Pragma("unroll") for (int j = 0; j < 8; ++j) gload16(gp[j], &lds[buf][lo[j]]); }
    #define ADV()    { _Pragma("unroll") for (int j = 0; j < 8; ++j) gp[j] += 32; }

    f32x4 acc[8][4];
    #pragma unroll
    for (int i = 0; i < 8; i++)
        #pragma unroll
        for (int j = 0; j < 4; j++) acc[i][j] = (f32x4)0.f;

    // prologue: tiles 0,1
    ST(0); ADV();
    ST(1); ADV();
    asm volatile("s_waitcnt vmcnt(8)" ::: "memory");   // tile 0 landed; tile 1 in flight
    __builtin_amdgcn_s_barrier();

    #define TRIP(AI, MI, NJ)                                                                          \
        acc[MI][NJ] = __builtin_amdgcn_mfma_f32_16x16x32_bf16(ah[AI], bh[NJ], acc[MI][NJ], 0, 0, 0);  \
        acc[MI][NJ] = __builtin_amdgcn_mfma_f32_16x16x32_bf16(ah[AI], bm[NJ], acc[MI][NJ], 0, 0, 0);  \
        acc[MI][NJ] = __builtin_amdgcn_mfma_f32_16x16x32_bf16(am[AI], bh[NJ], acc[MI][NJ], 0, 0, 0);

    for (int tt = 0; tt < 16; ++tt) {
        int p = tt & 1;
        bool pf = (tt < 14);
        const short* Ah = &lds[p][0];
        const short* Am = &lds[p][8192];
        const short* Bh = &lds[p][16384];
        const short* Bm = &lds[p][24576];

        s8 ah[4], am[4], bh[4], bm[4];

        // ---- phase 0: A-half0 (mi 0-3) + B-half0 (nj 0-1); MFMA quadrant (m0,n0) ----
        #pragma unroll
        for (int mi = 0; mi < 4; ++mi) {
            ah[mi] = ldfrag(Ah, mwoff + mi * 16 + l15, l);
            am[mi] = ldfrag(Am, mwoff + mi * 16 + l15, l);
        }
        bh[0] = ldfrag(Bh, nwoff + l15, l);      bm[0] = ldfrag(Bm, nwoff + l15, l);
        bh[1] = ldfrag(Bh, nwoff + 16 + l15, l); bm[1] = ldfrag(Bm, nwoff + 16 + l15, l);
        __builtin_amdgcn_s_barrier();
        asm volatile("s_waitcnt lgkmcnt(0)" ::: "memory");
        __builtin_amdgcn_sched_barrier(0);
        __builtin_amdgcn_s_setprio(1);
        #pragma unroll
        for (int mi = 0; mi < 4; ++mi) { TRIP(mi, mi, 0) TRIP(mi, mi, 1) }
        __builtin_amdgcn_s_setprio(0);
        __builtin_amdgcn_s_barrier();

        // ---- phase 1: B-half1 (nj 2-3); MFMA quadrant (m0,n1) ----
        bh[2] = ldfrag(Bh, nwoff + 32 + l15, l); bm[2] = ldfrag(Bm, nwoff + 32 + l15, l);
        bh[3] = ldfrag(Bh, nwoff + 48 + l15, l); bm[3] = ldfrag(Bm, nwoff + 48 + l15, l);
        __builtin_amdgcn_s_barrier();
        asm volatile("s_waitcnt lgkmcnt(0)" ::: "memory");
        __builtin_amdgcn_sched_barrier(0);
        __builtin_amdgcn_s_setprio(1);
        #pragma unroll
        for (int mi = 0; mi < 4; ++mi) { TRIP(mi, mi, 2) TRIP(mi, mi, 3) }
        __builtin_amdgcn_s_setprio(0);
        __builtin_amdgcn_s_barrier();

        // ---- phase 2: A-half1 (mi 4-7, reuse ah/am regs); MFMA quadrant (m1,n1) ----
        #pragma unroll
        for (int ai = 0; ai < 4; ++ai) {
            ah[ai] = ldfrag(Ah, mwoff + 64 + ai * 16 + l15, l);
            am[ai] = ldfrag(Am, mwoff + 64 + ai * 16 + l15, l);
        }
        __builtin_amdgcn_s_barrier();
        asm volatile("s_waitcnt lgkmcnt(0)" ::: "memory");
        __builtin_amdgcn_sched_barrier(0);
        __builtin_amdgcn_s_setprio(1);
        #pragma unroll
        for (int ai = 0; ai < 4; ++ai) { TRIP(ai, ai + 4, 2) TRIP(ai, ai + 4, 3) }
        __builtin_amdgcn_s_setprio(0);
        __builtin_amdgcn_s_barrier();

        // ---- phase 3: MFMA quadrant (m1,n0); stage tile tt+2 into current buffer ----
        __builtin_amdgcn_s_setprio(1);
        #pragma unroll
        for (int ai = 0; ai < 4; ++ai) { TRIP(ai, ai + 4, 0) TRIP(ai, ai + 4, 1) }
        __builtin_amdgcn_s_setprio(0);
        if (pf) {
            ST(p);                                             // buffer p fully read by now
            ADV();
            asm volatile("s_waitcnt vmcnt(8)" ::: "memory");   // tile tt+1 landed; tt+2 in flight
        } else {
            asm volatile("s_waitcnt vmcnt(0)" ::: "memory");   // tail drain
        }
        __builtin_amdgcn_s_barrier();
    }
    #undef TRIP
    #undef ST
    #undef ADV

    // epilogue: cos -> K = exp((c-1)*10); store out[b][m][n]; per-n max
    int hi4 = l >> 4;
    float n1v[4];
    int   ng[4];
    #pragma unroll
    for (int nj = 0; nj < 4; ++nj) {
        ng[nj]  = n0 + nwoff + nj * 16 + l15;
        n1v[nj] = (ng[nj] < N) ? norm1[b * N + ng[nj]] : 1.f;
    }
    float pmax[4] = {0.f, 0.f, 0.f, 0.f};
    size_t obase = (size_t)b * N * N;

    #pragma unroll
    for (int mi = 0; mi < 8; ++mi) {
        #pragma unroll
        for (int r = 0; r < 4; ++r) {
            int mg = m0 + mwoff + mi * 16 + hi4 * 4 + r;
            bool mok = (mg < N);
            float n2v = mok ? norm2[b * N + mg] : 1.f;
            #pragma unroll
            for (int nj = 0; nj < 4; ++nj) {
                float c = acc[mi][nj][r] / (n2v * n1v[nj] + EPS_K);
                float k = expf((c - 1.f) * INV_T);
                if (!mok) k = 0.f;
                pmax[nj] = fmaxf(pmax[nj], k);
                if (mok && ng[nj] < N)
                    out[obase + (size_t)mg * N + ng[nj]] = k;
            }
        }
    }
    #pragma unroll
    for (int nj = 0; nj < 4; ++nj) {
        float v = pmax[nj];
        v = fmaxf(v, __shfl_xor(v, 16, 64));
        v = fmaxf(v, __shfl_xor(v, 32, 64));
        if (hi4 == 0 && ng[nj] < N)
            atomicMax(&mx[b * N + ng[nj]], __float_as_uint(v));
    }
}

// ---------------- fp32 fallback GEMM (used if ws too small) ----------------
#define BK 16
#define BT 128
__global__ __launch_bounds__(256)
void gemm_exp_kernel(const float* __restrict__ fs1, const float* __restrict__ fs2,
                     const float* __restrict__ norm1, const float* __restrict__ norm2,
                     unsigned int* __restrict__ mx, float* __restrict__ out) {
    int m0 = blockIdx.x * BT, n0 = blockIdx.y * BT, b = blockIdx.z;
    int t = threadIdx.x, tx = t & 15, ty = t >> 4;
    __shared__ float Xs[BK][BT];
    __shared__ float Ys[BK][BT];
    __shared__ float red[BT][17];
    const float* Xb = fs1 + (size_t)b * D * N;
    const float* Yb = fs2 + (size_t)b * D * N;
    float acc[8][8];
    #pragma unroll
    for (int i = 0; i < 8; i++)
        #pragma unroll
        for (int j = 0; j < 8; j++) acc[i][j] = 0.f;
    int r0 = t >> 5, c4 = (t & 31) * 4;
    bool xok = (n0 + c4) < N, yok = (m0 + c4) < N;
    for (int kk = 0; kk < D; kk += BK) {
        #pragma unroll
        for (int rr = 0; rr < 2; rr++) {
            int r = r0 + rr * 8, d = kk + r;
            float4 xv = make_float4(0, 0, 0, 0), yv = make_float4(0, 0, 0, 0);
            if (xok) xv = *(const float4*)&Xb[(size_t)d * N + n0 + c4];
            if (yok) yv = *(const float4*)&Yb[(size_t)d * N + m0 + c4];
            *(float4*)&Xs[r][c4] = xv;
            *(float4*)&Ys[r][c4] = yv;
        }
        __syncthreads();
        #pragma unroll
        for (int d = 0; d < BK; d++) {
            float4 a0 = *(const float4*)&Xs[d][ty * 4];
            float4 a1 = *(const float4*)&Xs[d][64 + ty * 4];
            float4 b0 = *(const float4*)&Ys[d][tx * 4];
            float4 b1 = *(const float4*)&Ys[d][64 + tx * 4];
            float av[8] = {a0.x, a0.y, a0.z, a0.w, a1.x, a1.y, a1.z, a1.w};
            float bv[8] = {b0.x, b0.y, b0.z, b0.w, b1.x, b1.y, b1.z, b1.w};
            #pragma unroll
            for (int i = 0; i < 8; i++)
                #pragma unroll
                for (int j = 0; j < 8; j++)
                    acc[i][j] = fmaf(av[i], bv[j], acc[i][j]);
        }
        __syncthreads();
    }
    int ng[8], mg[8];
    float n1v[8], n2v[8];
    #pragma unroll
    for (int q = 0; q < 8; q++) {
        ng[q] = n0 + ((q < 4) ? (ty * 4 + q) : (64 + ty * 4 + q - 4));
        mg[q] = m0 + ((q < 4) ? (tx * 4 + q) : (64 + tx * 4 + q - 4));
        n1v[q] = (ng[q] < N) ? norm1[b * N + ng[q]] : 1.f;
        n2v[q] = (mg[q] < N) ? norm2[b * N + mg[q]] : 1.f;
    }
    float pmax[8];
    #pragma unroll
    for (int i = 0; i < 8; i++) pmax[i] = 0.f;
    size_t obase = (size_t)b * N * N;
    #pragma unroll
    for (int j = 0; j < 8; j++) {
        float kcol[8];
        #pragma unroll
        for (int i = 0; i < 8; i++) {
            float c = acc[i][j] / (n1v[i] * n2v[j] + EPS_K);
            float k = expf((c - 1.f) * INV_T);
            if (mg[j] >= N) k = 0.f;
            kcol[i] = k;
            pmax[i] = fmaxf(pmax[i], k);
        }
        if (mg[j] < N) {
            size_t rowb = obase + (size_t)mg[j] * N;
            float4 v0 = {kcol[0], kcol[1], kcol[2], kcol[3]};
            *(float4*)&out[rowb + ng[0]] = v0;
            if (ng[4] < N) {
                float4 v1 = {kcol[4], kcol[5], kcol[6], kcol[7]};
                *(float4*)&out[rowb + ng[4]] = v1;
            }
        }
    }
    #pragma unroll
    for (int q = 0; q < 8; q++) {
        int nloc = (q < 4) ? (ty * 4 + q) : (64 + ty * 4 + q - 4);
        red[nloc][tx] = pmax[q];
    }
    __syncthreads();
    if (t < BT) {
        float mval = red[t][0];
        #pragma unroll
        for (int x = 1; x < 16; x++) mval = fmaxf(mval, red[t][x]);
        int n = n0 + t;
        if (n < N) atomicMax(&mx[b * N + n], __float_as_uint(mval));
    }
}

// ---------------- Kernel D: fixup + band-candidate counting (no global list) ----------------
__global__ __launch_bounds__(256)
void fix_argmax_kernel(float* __restrict__ out, const unsigned int* __restrict__ mx,
                       int* __restrict__ bestm, unsigned int* __restrict__ candCount) {
    int nt = blockIdx.x;      // 0..6 (n chunks of 256)
    int mq = blockIdx.y;      // 0..31 (m chunks of 50)
    int b  = blockIdx.z;
    int t  = threadIdx.x;
    int n0 = nt * 256 + (t & 63) * 4;
    int moff = t >> 6;
    if (n0 >= N) return;      // N%4==0 -> full float4 valid or fully out

    float4 mxv = *(const float4*)&((const float*)mx)[b * N + n0];
    float4 th  = make_float4(mxv.x * BAND, mxv.y * BAND, mxv.z * BAND, mxv.w * BAND);
    size_t base = (size_t)b * N * N + n0;
    int mend = mq * 50 + 50;
    for (int m = mq * 50 + moff; m < mend; m += 4) {
        size_t idx = base + (size_t)m * N;
        float4 v = *(float4*)&out[idx];
        float4 o;
        o.x = (v.x - mxv.x) * SCALE_K;
        o.y = (v.y - mxv.y) * SCALE_K;
        o.z = (v.z - mxv.z) * SCALE_K;
        o.w = (v.w - mxv.w) * SCALE_K;
        *(float4*)&out[idx] = o;
        #pragma unroll
        for (int j = 0; j < 4; ++j) {
            float vv = (j == 0) ? v.x : (j == 1) ? v.y : (j == 2) ? v.z : v.w;
            float tt = (j == 0) ? th.x : (j == 1) ? th.y : (j == 2) ? th.z : th.w;
            if (vv >= tt) {
                int pix = b * N + n0 + j;
                atomicAdd(&candCount[pix], 1u);   // scattered, ~1 per pixel
                atomicMin(&bestm[pix], m);
            }
        }
    }
}

// ---------------- Kernel D2: exact refinement for multi-candidate pixels ----------------
__global__ __launch_bounds__(256)
void refine_kernel(const float* __restrict__ fs1, const float* __restrict__ fs2,
                   const float* __restrict__ norm1, const float* __restrict__ norm2,
                   const unsigned int* __restrict__ mx, const unsigned int* __restrict__ candCount,
                   int* __restrict__ bestm, const float* __restrict__ out) {
    int wv = (blockIdx.x * 256 + threadIdx.x) >> 6;   // global wave id, 800 waves
    int l  = threadIdx.x & 63;
    for (int pix = wv; pix < B * N; pix += 800) {
        if (candCount[pix] < 2) continue;             // unique band member == exact argmax
        int b = pix / N, n = pix % N;
        float mxv = __uint_as_float(mx[pix]);
        float gth = -(1.f - BAND) * SCALE_K * mxv;    // g >= gth <=> K >= BAND*mx; max has g==0
        const float* col = out + (size_t)b * N * N + n;
        const float* p1  = fs1 + (size_t)b * D * N + n;
        float n1 = norm1[pix];
        float bestc = -2.f;
        int   bi = 0;
        for (int it = 0; it < 25; ++it) {
            int m = it * 64 + l;
            float g = col[(size_t)m * N];
            unsigned long long mask = __ballot(g >= gth);
            while (mask) {
                int s = __ffsll(mask) - 1;
                mask &= mask - 1;
                int mc = it * 64 + s;
                const float* p2 = fs2 + (size_t)b * D * N + mc;
                float acc = 0.f;
                #pragma unroll
                for (int d8 = 0; d8 < 8; ++d8) {
                    int d = d8 * 64 + l;
                    acc = fmaf(p1[(size_t)d * N], p2[(size_t)d * N], acc);
                }
                #pragma unroll
                for (int off = 1; off < 64; off <<= 1)
                    acc += __shfl_xor(acc, off, 64);
                float cc = acc / (n1 * norm2[b * N + mc] + EPS_K);
                if (cc > bestc) { bestc = cc; bi = mc; }   // ascending m -> first-max tiebreak
            }
        }
        if (l == 0) bestm[pix] = bi;                  // one wave owns this pixel
    }
}

// ---------------- Kernel E: flow + certainty ----------------
__global__ __launch_bounds__(256)
void flow_kernel(float* __restrict__ out, const int* __restrict__ bestm) {
    int id = blockIdx.x * 256 + threadIdx.x;
    if (id >= B * N) return;
    int b = id / N, n = id % N;
    int bm = bestm[id];
    int i = bm / NRES, j = bm % NRES;
    const float step = 1.95f / 39.f;
    float gx = fmaf(step, (float)j, -0.975f);
    float gy = fmaf(step, (float)i, -0.975f);
    const size_t CERT_OFF = (size_t)B * N * N;
    const size_t FLOW_OFF = CERT_OFF + (size_t)B * N;
    out[CERT_OFF + id] = 0.f;
    out[FLOW_OFF + (size_t)(b * 2) * N + n]     = gx;
    out[FLOW_OFF + (size_t)(b * 2 + 1) * N + n] = gy;
}

extern "C" void kernel_launch(void* const* d_in, const int* in_sizes, int n_in,
                              void* d_out, int out_size, void* d_ws, size_t ws_size,
                              hipStream_t stream) {
    const float* fs1 = (const float*)d_in[0];
    const float* fs2 = (const float*)d_in[1];
    float* out = (float*)d_out;

    const size_t SPLIT = (size_t)B * NP * D;                 // elems per split array
    const size_t NEED  = 4 * SPLIT * sizeof(short)           // Yh,Ym,Xh,Xm
                       + 5 * (size_t)B * N * 4 + 64;         // norm1,norm2,mx,bestm,candCount

    if (ws_size >= NEED) {
        short* Yh = (short*)d_ws;
        short* Ym = Yh + SPLIT;
        short* Xh = Ym + SPLIT;
        short* Xm = Xh + SPLIT;
        float* norm1 = (float*)(Xm + SPLIT);
        float* norm2 = norm1 + B * N;
        unsigned int* mx = (unsigned int*)(norm2 + B * N);
        int* bestm = (int*)(mx + B * N);
        unsigned int* candCount = (unsigned int*)(bestm + B * N);
        float* partial = out;    // scratch inside gm_cls region, overwritten by gemm

        hipMemsetAsync(mx, 0, B * N * sizeof(unsigned int), stream);
        hipMemsetAsync(bestm, 0x7f, B * N * sizeof(int), stream);
        hipMemsetAsync(candCount, 0, B * N * sizeof(unsigned int), stream);

        split_transpose_kernel<<<dim3(26, 8, 16), 256, 0, stream>>>(
            fs1, fs2, Xh, Xm, Yh, Ym, partial);
        norms_reduce_kernel<<<dim3(100), 256, 0, stream>>>(partial, norm1, norm2);
        gemm_mfma256_kernel<<<dim3(392), 512, 0, stream>>>(Yh, Ym, Xh, Xm,
                                                           norm1, norm2, mx, out);
        fix_argmax_kernel<<<dim3(7, 32, B), 256, 0, stream>>>(out, mx, bestm, candCount);
        refine_kernel<<<dim3(200), 256, 0, stream>>>(fs1, fs2, norm1, norm2,
                                                     mx, candCount, bestm, out);
        flow_kernel<<<dim3((B * N + 255) / 256), 256, 0, stream>>>(out, bestm);
    } else {
        float* norm1 = (float*)d_ws;
        float* norm2 = norm1 + B * N;
        unsigned int* mx = (unsigned int*)(norm2 + B * N);
        int* bestm = (int*)(mx + B * N);
        unsigned int* candCount = (unsigned int*)(bestm + B * N);

        hipMemsetAsync(mx, 0, B * N * sizeof(unsigned int), stream);
        hipMemsetAsync(bestm, 0x7f, B * N * sizeof(int), stream);
        hipMemsetAsync(candCount, 0, B * N * sizeof(unsigned int), stream);

        norms_kernel<<<dim3(2 * B * 25), 256, 0, stream>>>(fs1, fs2, norm1, norm2);
        gemm_exp_kernel<<<dim3(13, 13, B), 256, 0, stream>>>(fs1, fs2, norm1, norm2, mx, out);
        fix_argmax_kernel<<<dim3(7, 32, B), 256, 0, stream>>>(out, mx, bestm, candCount);
        refine_kernel<<<dim3(200), 256, 0, stream>>>(fs1, fs2, norm1, norm2,
                                                     mx, candCount, bestm, out);
        flow_kernel<<<dim3((B * N + 255) / 256), 256, 0, stream>>>(out, bestm);
    }
}

// Round 8
// 165.148 us; speedup vs baseline: 1.2451x; 1.2451x over previous
//
#include <hip/hip_runtime.h>
#include <math.h>

#define B 8
#define D 512
#define N 1600
#define NP 1664      // padded N (13 * 128) -- physical row count of split arrays
#define NRES 40

static constexpr float EPS_K   = 1e-6f;
static constexpr float INV_T   = 10.0f;  // 1/T
static constexpr float SCALE_K = 10.0f;
static constexpr float BAND    = 0.999f; // candidate band (rel. to max K)
static constexpr float L2E10   = 14.4269504089f; // 10*log2(e)

using f32x4 = __attribute__((ext_vector_type(4))) float;
using s8    = __attribute__((ext_vector_type(8))) short;

// ---------------- helpers ----------------
__device__ __forceinline__ unsigned short b16rn(float v) {
    unsigned int u = __float_as_uint(v);
    return (unsigned short)((u + 0x7fffu + ((u >> 16) & 1u)) >> 16);
}
__device__ __forceinline__ float b2f(unsigned short s) {
    return __uint_as_float(((unsigned int)s) << 16);
}
__device__ __forceinline__ void gload16(const void* g, void* l) {
    __builtin_amdgcn_global_load_lds(
        (const __attribute__((address_space(1))) void*)g,
        (__attribute__((address_space(3))) void*)l, 16, 0, 0);
}

// ---------------- Kernel A: split fp32 -> hi/mid bf16 transposed + norm partials ----------------
__global__ __launch_bounds__(256)
void split_transpose_kernel(const float* __restrict__ f1, const float* __restrict__ f2,
                            short* __restrict__ Xh, short* __restrict__ Xm,
                            short* __restrict__ Yh, short* __restrict__ Ym,
                            float* __restrict__ partial) {
    int bx = blockIdx.x;           // n-tile of 64 (0..25, covers NP)
    int by = blockIdx.y;           // d-tile of 64 (0..7)
    int bz = blockIdx.z;
    int b = bz & 7, which = bz >> 3;
    const float* src = which ? f2 : f1;
    short* oh = which ? Yh : Xh;
    short* om = which ? Ym : Xm;

    __shared__ float Ts[64][65];
    __shared__ float red[64][17];
    int t = threadIdx.x;
    int n0 = bx * 64, d0 = by * 64;
    bool valid = (n0 < N);         // bx==25 is the zero-pad tile
    int c4 = (t & 15) * 4, g16 = t >> 4;

    #pragma unroll
    for (int p = 0; p < 4; ++p) {
        int dl = g16 + p * 16;
        float4 v = make_float4(0.f, 0.f, 0.f, 0.f);
        if (valid) v = *(const float4*)&src[((size_t)b * D + d0 + dl) * N + n0 + c4];
        Ts[dl][c4 + 0] = v.x; Ts[dl][c4 + 1] = v.y;
        Ts[dl][c4 + 2] = v.z; Ts[dl][c4 + 3] = v.w;
    }
    __syncthreads();
    #pragma unroll
    for (int p = 0; p < 4; ++p) {
        int nl = g16 + p * 16;
        unsigned int hh[2], mm_[2];
        float ssp = 0.f;
        #pragma unroll
        for (int q = 0; q < 2; ++q) {
            unsigned int hw = 0, mw = 0;
            #pragma unroll
            for (int i = 0; i < 2; ++i) {
                float v = Ts[c4 + q * 2 + i][nl];
                ssp = fmaf(v, v, ssp);
                unsigned short h = b16rn(v);
                float r1 = v - b2f(h);
                unsigned short m_ = b16rn(r1);
                hw |= ((unsigned int)h) << (16 * i);
                mw |= ((unsigned int)m_) << (16 * i);
            }
            hh[q] = hw; mm_[q] = mw;
        }
        red[nl][c4 >> 2] = ssp;
        size_t o = ((size_t)b * NP + n0 + nl) * D + d0 + c4;
        *(uint2*)&oh[o] = make_uint2(hh[0], hh[1]);
        *(uint2*)&om[o] = make_uint2(mm_[0], mm_[1]);
    }
    __syncthreads();
    if (t < 64) {
        float s = 0.f;
        #pragma unroll
        for (int g = 0; g < 16; ++g) s += red[t][g];
        partial[(((size_t)which * 8 + b) * 8 + by) * NP + n0 + t] = s;
    }
}

// ---------------- Kernel A2: reduce norm partials ----------------
__global__ __launch_bounds__(256)
void norms_reduce_kernel(const float* __restrict__ partial,
                         float* __restrict__ norm1, float* __restrict__ norm2) {
    int id = blockIdx.x * 256 + threadIdx.x;   // over 2*B*N
    if (id >= 2 * B * N) return;
    int which = id / (B * N);
    int r = id % (B * N);
    int b = r / N, n = r % N;
    float s = 0.f;
    #pragma unroll
    for (int dt = 0; dt < 8; ++dt)
        s += partial[(((size_t)which * 8 + b) * 8 + dt) * NP + n];
    (which ? norm2 : norm1)[b * N + n] = sqrtf(s);
}

// ---------------- Kernel B (fallback path): column norms ----------------
__global__ __launch_bounds__(256)
void norms_kernel(const float* __restrict__ fs1, const float* __restrict__ fs2,
                  float* __restrict__ norm1, float* __restrict__ norm2) {
    int bid   = blockIdx.x;
    int ntile = bid % 25;
    int b     = (bid / 25) % B;
    int which = bid / (25 * B);
    const float* src = which ? fs2 : fs1;
    float*       dst = which ? norm2 : norm1;

    int t = threadIdx.x, nl = t & 63, doff = t >> 6;
    int n = ntile * 64 + nl;
    const float* base = src + (size_t)b * D * N + n;
    float acc = 0.f;
    for (int d = doff; d < D; d += 4) {
        float v = base[(size_t)d * N];
        acc = fmaf(v, v, acc);
    }
    __shared__ float red[4][64];
    red[doff][nl] = acc;
    __syncthreads();
    if (t < 64) {
        float s = red[0][t] + red[1][t] + red[2][t] + red[3][t];
        dst[b * N + ntile * 64 + t] = sqrtf(s);
    }
}

// ---------------- Kernel C: 3-product bf16x3 MFMA GEMM, 128x128, single-buffer, 4 blocks/CU ----------------
__device__ __forceinline__ s8 ldfrag(const short* tile, int row, int l) {
    int s = ((l >> 4) ^ (row >> 1)) & 3;   // bank-spread XOR swizzle
    return *(const s8*)(tile + row * 32 + s * 8);
}

__global__ __launch_bounds__(256, 4)
void gemm_mfma_kernel(const short* __restrict__ Yh, const short* __restrict__ Ym,
                      const short* __restrict__ Xh, const short* __restrict__ Xm,
                      const float* __restrict__ norm1, const float* __restrict__ norm2,
                      unsigned int* __restrict__ mx, float* __restrict__ out) {
    // single buffer: [Ah | Am | Bh | Bm], each 128x32 bf16 (8KB) = 32KB -> 4 blocks/CU
    __shared__ short lds[16384];

    int lin = blockIdx.x;          // 1352 = 8 XCD * 169
    int b    = lin & 7;            // one batch per XCD (T1)
    int rem  = lin >> 3;           // 0..168
    int mblk = rem % 13;           // m fastest -> X-panel L2 reuse
    int nblk = rem / 13;           // 0..12
    int m0 = mblk * 128, n0 = nblk * 128;

    int t = threadIdx.x, l = t & 63, w = t >> 6;
    int mwoff = (w & 1) * 64;      // wave tile 64x64
    int nwoff = (w >> 1) * 64;
    size_t bNP = (size_t)b * NP;
    int l15 = l & 15;

    // --- staging: wave w stages tile w (0=Ah,1=Am,2=Bh,3=Bm), 8 gload16/thread ---
    const short* tsrc = (w == 0) ? Yh : (w == 1) ? Ym : (w == 2) ? Xh : Xm;
    int rows0 = (w < 2) ? m0 : n0;
    const short* gp[8];
    #pragma unroll
    for (int j = 0; j < 8; ++j) {
        int row  = j * 16 + (l >> 2);
        int slot = ((l & 3) ^ (row >> 1)) & 3;
        gp[j] = tsrc + (bNP + rows0 + row) * (size_t)D + slot * 8;
    }

    #define ST()                                               \
    {   _Pragma("unroll")                                      \
        for (int j = 0; j < 8; ++j) {                          \
            gload16(gp[j], &lds[w * 4096 + j * 512]);          \
            gp[j] += 32;                                       \
        }                                                      \
    }

    f32x4 acc[4][4];
    #pragma unroll
    for (int i = 0; i < 4; i++)
        #pragma unroll
        for (int j = 0; j < 4; j++) acc[i][j] = (f32x4)0.f;

    const short* Ah = &lds[0];
    const short* Am = &lds[4096];
    const short* Bh = &lds[8192];
    const short* Bm = &lds[12288];

    for (int tt = 0; tt < 16; ++tt) {
        ST();                                              // stage K-tile tt
        asm volatile("s_waitcnt vmcnt(0)" ::: "memory");
        __builtin_amdgcn_s_barrier();                      // all 4 tiles visible
        asm volatile("" ::: "memory");

        s8 bh[4], bm[4];
        #pragma unroll
        for (int nj = 0; nj < 4; ++nj) {
            int nrow = nwoff + nj * 16 + l15;
            bh[nj] = ldfrag(Bh, nrow, l);
            bm[nj] = ldfrag(Bm, nrow, l);
        }
        __builtin_amdgcn_s_setprio(1);
        #pragma unroll
        for (int mi = 0; mi < 4; ++mi) {
            int mrow = mwoff + mi * 16 + l15;
            s8 ah = ldfrag(Ah, mrow, l);
            s8 am = ldfrag(Am, mrow, l);
            #pragma unroll
            for (int nj = 0; nj < 4; ++nj) {
                f32x4 c = acc[mi][nj];
                c = __builtin_amdgcn_mfma_f32_16x16x32_bf16(ah, bh[nj], c, 0, 0, 0);
                c = __builtin_amdgcn_mfma_f32_16x16x32_bf16(ah, bm[nj], c, 0, 0, 0);
                c = __builtin_amdgcn_mfma_f32_16x16x32_bf16(am, bh[nj], c, 0, 0, 0);
                acc[mi][nj] = c;
            }
        }
        __builtin_amdgcn_s_setprio(0);
        asm volatile("s_waitcnt lgkmcnt(0)" ::: "memory");  // LDS reads retired before overwrite
        __builtin_amdgcn_s_barrier();
    }
    #undef ST

    // epilogue: c = acc*rn1*rn2; K = exp2((c-1)*10*log2e); store out[b][m][n]; per-n max
    int hi4 = l >> 4;
    float rn1v[4];
    int   ng[4];
    #pragma unroll
    for (int nj = 0; nj < 4; ++nj) {
        ng[nj]  = n0 + nwoff + nj * 16 + l15;
        float n1 = (ng[nj] < N) ? norm1[b * N + ng[nj]] : 1.f;
        rn1v[nj] = __builtin_amdgcn_rcpf(n1);
    }
    float pmax[4] = {0.f, 0.f, 0.f, 0.f};
    size_t obase = (size_t)b * N * N;

    #pragma unroll
    for (int mi = 0; mi < 4; ++mi) {
        #pragma unroll
        for (int r = 0; r < 4; ++r) {
            int mg = m0 + mwoff + mi * 16 + hi4 * 4 + r;
            bool mok = (mg < N);
            float rn2 = mok ? __builtin_amdgcn_rcpf(norm2[b * N + mg]) : 1.f;
            #pragma unroll
            for (int nj = 0; nj < 4; ++nj) {
                float c = acc[mi][nj][r] * rn2 * rn1v[nj];
                float k = exp2f((c - 1.f) * L2E10);
                if (!mok) k = 0.f;
                pmax[nj] = fmaxf(pmax[nj], k);
                if (mok && ng[nj] < N)
                    out[obase + (size_t)mg * N + ng[nj]] = k;
            }
        }
    }
    #pragma unroll
    for (int nj = 0; nj < 4; ++nj) {
        float v = pmax[nj];
        v = fmaxf(v, __shfl_xor(v, 16, 64));
        v = fmaxf(v, __shfl_xor(v, 32, 64));
        if (hi4 == 0 && ng[nj] < N)
            atomicMax(&mx[b * N + ng[nj]], __float_as_uint(v));
    }
}

// ---------------- fp32 fallback GEMM (used if ws too small) ----------------
#define BK 16
#define BT 128
__global__ __launch_bounds__(256)
void gemm_exp_kernel(const float* __restrict__ fs1, const float* __restrict__ fs2,
                     const float* __restrict__ norm1, const float* __restrict__ norm2,
                     unsigned int* __restrict__ mx, float* __restrict__ out) {
    int m0 = blockIdx.x * BT, n0 = blockIdx.y * BT, b = blockIdx.z;
    int t = threadIdx.x, tx = t & 15, ty = t >> 4;
    __shared__ float Xs[BK][BT];
    __shared__ float Ys[BK][BT];
    __shared__ float red[BT][17];
    const float* Xb = fs1 + (size_t)b * D * N;
    const float* Yb = fs2 + (size_t)b * D * N;
    float acc[8][8];
    #pragma unroll
    for (int i = 0; i < 8; i++)
        #pragma unroll
        for (int j = 0; j < 8; j++) acc[i][j] = 0.f;
    int r0 = t >> 5, c4 = (t & 31) * 4;
    bool xok = (n0 + c4) < N, yok = (m0 + c4) < N;
    for (int kk = 0; kk < D; kk += BK) {
        #pragma unroll
        for (int rr = 0; rr < 2; rr++) {
            int r = r0 + rr * 8, d = kk + r;
            float4 xv = make_float4(0, 0, 0, 0), yv = make_float4(0, 0, 0, 0);
            if (xok) xv = *(const float4*)&Xb[(size_t)d * N + n0 + c4];
            if (yok) yv = *(const float4*)&Yb[(size_t)d * N + m0 + c4];
            *(float4*)&Xs[r][c4] = xv;
            *(float4*)&Ys[r][c4] = yv;
        }
        __syncthreads();
        #pragma unroll
        for (int d = 0; d < BK; d++) {
            float4 a0 = *(const float4*)&Xs[d][ty * 4];
            float4 a1 = *(const float4*)&Xs[d][64 + ty * 4];
            float4 b0 = *(const float4*)&Ys[d][tx * 4];
            float4 b1 = *(const float4*)&Ys[d][64 + tx * 4];
            float av[8] = {a0.x, a0.y, a0.z, a0.w, a1.x, a1.y, a1.z, a1.w};
            float bv[8] = {b0.x, b0.y, b0.z, b0.w, b1.x, b1.y, b1.z, b1.w};
            #pragma unroll
            for (int i = 0; i < 8; i++)
                #pragma unroll
                for (int j = 0; j < 8; j++)
                    acc[i][j] = fmaf(av[i], bv[j], acc[i][j]);
        }
        __syncthreads();
    }
    int ng[8], mg[8];
    float n1v[8], n2v[8];
    #pragma unroll
    for (int q = 0; q < 8; q++) {
        ng[q] = n0 + ((q < 4) ? (ty * 4 + q) : (64 + ty * 4 + q - 4));
        mg[q] = m0 + ((q < 4) ? (tx * 4 + q) : (64 + tx * 4 + q - 4));
        n1v[q] = (ng[q] < N) ? norm1[b * N + ng[q]] : 1.f;
        n2v[q] = (mg[q] < N) ? norm2[b * N + mg[q]] : 1.f;
    }
    float pmax[8];
    #pragma unroll
    for (int i = 0; i < 8; i++) pmax[i] = 0.f;
    size_t obase = (size_t)b * N * N;
    #pragma unroll
    for (int j = 0; j < 8; j++) {
        float kcol[8];
        #pragma unroll
        for (int i = 0; i < 8; i++) {
            float c = acc[i][j] / (n1v[i] * n2v[j] + EPS_K);
            float k = expf((c - 1.f) * INV_T);
            if (mg[j] >= N) k = 0.f;
            kcol[i] = k;
            pmax[i] = fmaxf(pmax[i], k);
        }
        if (mg[j] < N) {
            size_t rowb = obase + (size_t)mg[j] * N;
            float4 v0 = {kcol[0], kcol[1], kcol[2], kcol[3]};
            *(float4*)&out[rowb + ng[0]] = v0;
            if (ng[4] < N) {
                float4 v1 = {kcol[4], kcol[5], kcol[6], kcol[7]};
                *(float4*)&out[rowb + ng[4]] = v1;
            }
        }
    }
    #pragma unroll
    for (int q = 0; q < 8; q++) {
        int nloc = (q < 4) ? (ty * 4 + q) : (64 + ty * 4 + q - 4);
        red[nloc][tx] = pmax[q];
    }
    __syncthreads();
    if (t < BT) {
        float mval = red[t][0];
        #pragma unroll
        for (int x = 1; x < 16; x++) mval = fmaxf(mval, red[t][x]);
        int n = n0 + t;
        if (n < N) atomicMax(&mx[b * N + n], __float_as_uint(mval));
    }
}

// ---------------- Kernel D: fixup + band-candidate counting (no global list) ----------------
__global__ __launch_bounds__(256)
void fix_argmax_kernel(float* __restrict__ out, const unsigned int* __restrict__ mx,
                       int* __restrict__ bestm, unsigned int* __restrict__ candCount) {
    int nt = blockIdx.x;      // 0..6 (n chunks of 256)
    int mq = blockIdx.y;      // 0..31 (m chunks of 50)
    int b  = blockIdx.z;
    int t  = threadIdx.x;
    int n0 = nt * 256 + (t & 63) * 4;
    int moff = t >> 6;
    if (n0 >= N) return;      // N%4==0 -> full float4 valid or fully out

    float4 mxv = *(const float4*)&((const float*)mx)[b * N + n0];
    float4 th  = make_float4(mxv.x * BAND, mxv.y * BAND, mxv.z * BAND, mxv.w * BAND);
    size_t base = (size_t)b * N * N + n0;
    int mend = mq * 50 + 50;
    for (int m = mq * 50 + moff; m < mend; m += 4) {
        size_t idx = base + (size_t)m * N;
        float4 v = *(float4*)&out[idx];
        float4 o;
        o.x = (v.x - mxv.x) * SCALE_K;
        o.y = (v.y - mxv.y) * SCALE_K;
        o.z = (v.z - mxv.z) * SCALE_K;
        o.w = (v.w - mxv.w) * SCALE_K;
        *(float4*)&out[idx] = o;
        #pragma unroll
        for (int j = 0; j < 4; ++j) {
            float vv = (j == 0) ? v.x : (j == 1) ? v.y : (j == 2) ? v.z : v.w;
            float tt = (j == 0) ? th.x : (j == 1) ? th.y : (j == 2) ? th.z : th.w;
            if (vv >= tt) {
                int pix = b * N + n0 + j;
                atomicAdd(&candCount[pix], 1u);   // scattered, ~1 per pixel
                atomicMin(&bestm[pix], m);
            }
        }
    }
}

// ---------------- Kernel D2: exact refinement for multi-candidate pixels ----------------
__global__ __launch_bounds__(256)
void refine_kernel(const float* __restrict__ fs1, const float* __restrict__ fs2,
                   const float* __restrict__ norm1, const float* __restrict__ norm2,
                   const unsigned int* __restrict__ mx, const unsigned int* __restrict__ candCount,
                   int* __restrict__ bestm, const float* __restrict__ out) {
    int wv = (blockIdx.x * 256 + threadIdx.x) >> 6;   // global wave id, 800 waves
    int l  = threadIdx.x & 63;
    for (int pix = wv; pix < B * N; pix += 800) {
        if (candCount[pix] < 2) continue;             // unique band member == exact argmax
        int b = pix / N, n = pix % N;
        float mxv = __uint_as_float(mx[pix]);
        float gth = -(1.f - BAND) * SCALE_K * mxv;    // g >= gth <=> K >= BAND*mx; max has g==0
        const float* col = out + (size_t)b * N * N + n;
        const float* p1  = fs1 + (size_t)b * D * N + n;
        float n1 = norm1[pix];
        float bestc = -2.f;
        int   bi = 0;
        for (int it = 0; it < 25; ++it) {
            int m = it * 64 + l;
            float g = col[(size_t)m * N];
            unsigned long long mask = __ballot(g >= gth);
            while (mask) {
                int s = __ffsll(mask) - 1;
                mask &= mask - 1;
                int mc = it * 64 + s;
                const float* p2 = fs2 + (size_t)b * D * N + mc;
                float acc = 0.f;
                #pragma unroll
                for (int d8 = 0; d8 < 8; ++d8) {
                    int d = d8 * 64 + l;
                    acc = fmaf(p1[(size_t)d * N], p2[(size_t)d * N], acc);
                }
                #pragma unroll
                for (int off = 1; off < 64; off <<= 1)
                    acc += __shfl_xor(acc, off, 64);
                float cc = acc / (n1 * norm2[b * N + mc] + EPS_K);
                if (cc > bestc) { bestc = cc; bi = mc; }   // ascending m -> first-max tiebreak
            }
        }
        if (l == 0) bestm[pix] = bi;                  // one wave owns this pixel
    }
}

// ---------------- Kernel E: flow + certainty ----------------
__global__ __launch_bounds__(256)
void flow_kernel(float* __restrict__ out, const int* __restrict__ bestm) {
    int id = blockIdx.x * 256 + threadIdx.x;
    if (id >= B * N) return;
    int b = id / N, n = id % N;
    int bm = bestm[id];
    int i = bm / NRES, j = bm % NRES;
    const float step = 1.95f / 39.f;
    float gx = fmaf(step, (float)j, -0.975f);
    float gy = fmaf(step, (float)i, -0.975f);
    const size_t CERT_OFF = (size_t)B * N * N;
    const size_t FLOW_OFF = CERT_OFF + (size_t)B * N;
    out[CERT_OFF + id] = 0.f;
    out[FLOW_OFF + (size_t)(b * 2) * N + n]     = gx;
    out[FLOW_OFF + (size_t)(b * 2 + 1) * N + n] = gy;
}

extern "C" void kernel_launch(void* const* d_in, const int* in_sizes, int n_in,
                              void* d_out, int out_size, void* d_ws, size_t ws_size,
                              hipStream_t stream) {
    const float* fs1 = (const float*)d_in[0];
    const float* fs2 = (const float*)d_in[1];
    float* out = (float*)d_out;

    const size_t SPLIT = (size_t)B * NP * D;                 // elems per split array
    const size_t NEED  = 4 * SPLIT * sizeof(short)           // Yh,Ym,Xh,Xm
                       + 5 * (size_t)B * N * 4 + 64;         // norm1,norm2,mx,bestm,candCount

    if (ws_size >= NEED) {
        short* Yh = (short*)d_ws;
        short* Ym = Yh + SPLIT;
        short* Xh = Ym + SPLIT;
        short* Xm = Xh + SPLIT;
        float* norm1 = (float*)(Xm + SPLIT);
        float* norm2 = norm1 + B * N;
        unsigned int* mx = (unsigned int*)(norm2 + B * N);
        int* bestm = (int*)(mx + B * N);
        unsigned int* candCount = (unsigned int*)(bestm + B * N);
        float* partial = out;    // scratch inside gm_cls region, overwritten by gemm

        hipMemsetAsync(mx, 0, B * N * sizeof(unsigned int), stream);
        hipMemsetAsync(bestm, 0x7f, B * N * sizeof(int), stream);
        hipMemsetAsync(candCount, 0, B * N * sizeof(unsigned int), stream);

        split_transpose_kernel<<<dim3(26, 8, 16), 256, 0, stream>>>(
            fs1, fs2, Xh, Xm, Yh, Ym, partial);
        norms_reduce_kernel<<<dim3(100), 256, 0, stream>>>(partial, norm1, norm2);
        gemm_mfma_kernel<<<dim3(1352), 256, 0, stream>>>(Yh, Ym, Xh, Xm,
                                                         norm1, norm2, mx, out);
        fix_argmax_kernel<<<dim3(7, 32, B), 256, 0, stream>>>(out, mx, bestm, candCount);
        refine_kernel<<<dim3(200), 256, 0, stream>>>(fs1, fs2, norm1, norm2,
                                                     mx, candCount, bestm, out);
        flow_kernel<<<dim3((B * N + 255) / 256), 256, 0, stream>>>(out, bestm);
    } else {
        float* norm1 = (float*)d_ws;
        float* norm2 = norm1 + B * N;
        unsigned int* mx = (unsigned int*)(norm2 + B * N);
        int* bestm = (int*)(mx + B * N);
        unsigned int* candCount = (unsigned int*)(bestm + B * N);

        hipMemsetAsync(mx, 0, B * N * sizeof(unsigned int), stream);
        hipMemsetAsync(bestm, 0x7f, B * N * sizeof(int), stream);
        hipMemsetAsync(candCount, 0, B * N * sizeof(unsigned int), stream);

        norms_kernel<<<dim3(2 * B * 25), 256, 0, stream>>>(fs1, fs2, norm1, norm2);
        gemm_exp_kernel<<<dim3(13, 13, B), 256, 0, stream>>>(fs1, fs2, norm1, norm2, mx, out);
        fix_argmax_kernel<<<dim3(7, 32, B), 256, 0, stream>>>(out, mx, bestm, candCount);
        refine_kernel<<<dim3(200), 256, 0, stream>>>(fs1, fs2, norm1, norm2,
                                                     mx, candCount, bestm, out);
        flow_kernel<<<dim3((B * N + 255) / 256), 256, 0, stream>>>(out, bestm);
    }
}